// Round 8
// baseline (236.530 us; speedup 1.0000x reference)
//
#include <hip/hip_runtime.h>
#include <hip/hip_bf16.h>
#include <stdint.h>

// Problem constants: NA=NT=1024, A_DIM=E_DIM=128, L=128, K = L*128 = 16384

typedef short bf16x8 __attribute__((ext_vector_type(8)));
typedef float f32x4  __attribute__((ext_vector_type(4)));

#define GLD16(g, l) __builtin_amdgcn_global_load_lds( \
    (const __attribute__((address_space(1))) void*)(uintptr_t)(g), \
    (__attribute__((address_space(3))) void*)(uintptr_t)(l), 16, 0, 0)

#define BF_LO(v) __uint_as_float((v) << 16)
#define BF_HI(v) __uint_as_float((v) & 0xffff0000u)

// ---------------- prep: transpose inputs [1024][1024] -> inputsT ----------------
__global__ __launch_bounds__(256) void transpose_int_kernel(const int* __restrict__ in,
                                                            int* __restrict__ out) {
    __shared__ int tile[32][33];
    int b = blockIdx.x;              // 1024 tiles
    int tr = b >> 5, tc = b & 31;
    int r0 = tr * 32, c0 = tc * 32;
    int tx = threadIdx.x & 31, ty = threadIdx.x >> 5;
#pragma unroll
    for (int p = 0; p < 4; ++p)
        tile[ty + p * 8][tx] = in[(size_t)(r0 + ty + p * 8) * 1024 + c0 + tx];
    __syncthreads();
#pragma unroll
    for (int p = 0; p < 4; ++p) {
        int cc = ty + p * 8;
        out[(size_t)(c0 + cc) * 1024 + r0 + tx] = tile[tx][cc];
    }
}

// ------------- prep: transpose+cast weights f32 [16384][128] -> bf16 [128][16384] -------------
__global__ __launch_bounds__(256) void transpose_w_kernel(const float* __restrict__ W0,
                                                          const float* __restrict__ W1,
                                                          uint16_t* __restrict__ O0,
                                                          uint16_t* __restrict__ O1) {
    __shared__ float tile[32][33];
    int b = blockIdx.x;              // 4096 tiles (2048 per weight)
    const float* W = W0;
    uint16_t* O = O0;
    if (b >= 2048) { b -= 2048; W = W1; O = O1; }
    int tr = b >> 2, tc = b & 3;
    int r0 = tr * 32, c0 = tc * 32;
    int tx = threadIdx.x & 31, ty = threadIdx.x >> 5;
#pragma unroll
    for (int p = 0; p < 4; ++p)
        tile[ty + p * 8][tx] = W[(size_t)(r0 + ty + p * 8) * 128 + c0 + tx];
    __syncthreads();
#pragma unroll
    for (int p = 0; p < 4; ++p) {
        int cc = ty + p * 8;
        __hip_bfloat16 h = __float2bfloat16(tile[tx][cc]);
        O[(size_t)(c0 + cc) * 16384 + r0 + tx] = *(uint16_t*)&h;
    }
}

// ---------------- prep: CSR build — parallel deterministic counting sort ----------------
__global__ __launch_bounds__(128) void csr_build_kernel(const int* __restrict__ inA,
                                                        const int* __restrict__ inT,
                                                        uint16_t* __restrict__ idxA,
                                                        uint16_t* __restrict__ idxT,
                                                        int* __restrict__ offA,
                                                        int* __restrict__ offT) {
    __shared__ uint16_t chist[128][128];  // 32 KiB [chunk][label]
    __shared__ int lab[1024];
    __shared__ int tot[128];
    __shared__ int off[128];
    int b = blockIdx.x;
    const int* in = inA; uint16_t* idx = idxA; int* offo = offA; int row = b;
    if (b >= 1024) { in = inT; idx = idxT; offo = offT; row = b - 1024; }
    const int c = threadIdx.x;            // 0..127

    for (int i = c; i < 8192; i += 128) ((uint32_t*)chist)[i] = 0;
    for (int i = c; i < 1024; i += 128) lab[i] = in[(size_t)row * 1024 + i];
    __syncthreads();

    int mylab[8], rloc[8];
#pragma unroll
    for (int k = 0; k < 8; ++k) {
        int l = lab[c * 8 + k];
        mylab[k] = l;
        rloc[k] = chist[c][l];
        chist[c][l] = (uint16_t)(rloc[k] + 1);
    }
    __syncthreads();

    {   // column prefix over chunks: thread c owns label l=c
        int run = 0;
#pragma unroll 4
        for (int ch = 0; ch < 128; ++ch) {
            int v = chist[ch][c];
            chist[ch][c] = (uint16_t)run;
            run += v;
        }
        tot[c] = run;
    }
    __syncthreads();
    if (c == 0) {
        int s = 0;
#pragma unroll 4
        for (int l = 0; l < 128; ++l) { off[l] = s; s += tot[l]; }
    }
    __syncthreads();
    offo[(size_t)row * 128 + c] = off[c];
#pragma unroll
    for (int k = 0; k < 8; ++k) {
        int l = mylab[k];
        int pos = off[l] + (int)chist[c][l] + rloc[k];
        idx[(size_t)row * 1024 + pos] = (uint16_t)(c * 8 + k);
    }
}

// ---------------- prep: init output + bf16 mirrors (incl. zero row 1024) ----------------
__global__ __launch_bounds__(256) void init_out_kernel(const float* __restrict__ fa,
                                                       const float* __restrict__ ft,
                                                       float* __restrict__ out,
                                                       uint16_t* __restrict__ srcAb,
                                                       uint16_t* __restrict__ srcTb) {
    int i = blockIdx.x * 256 + threadIdx.x;   // grid 2048 -> 524288
    int r = i >> 8, c = i & 255;
    float v = 0.f;
    if (c < 128) {
        v = (r < 1024) ? fa[(size_t)r * 128 + c] : ft[(size_t)(r - 1024) * 128 + c];
        __hip_bfloat16 h = __float2bfloat16(v);
        if (r < 1024) srcAb[(size_t)r * 128 + c] = *(uint16_t*)&h;
        else          srcTb[(size_t)(r - 1024) * 128 + c] = *(uint16_t*)&h;
    }
    out[i] = v;
    if (i < 64) {   // dummy zero row (index 1024) used for segment padding
        ((uint32_t*)(srcAb + 1024 * 128))[i] = 0;
        ((uint32_t*)(srcTb + 1024 * 128))[i] = 0;
    }
}

// ---------------- reduce partials + update state + emit bf16 mirror ----------------
__global__ __launch_bounds__(256) void reduce_mirror_kernel(const float* __restrict__ partial,
                                                            float* __restrict__ state,
                                                            uint16_t* __restrict__ mirror) {
    const int r = blockIdx.x * 8 + (threadIdx.x >> 5);   // grid 128 -> rows 0..1023
    const int c4 = (threadIdx.x & 31) * 4;               // col group of 4
    const f32x4* p = (const f32x4*)(partial + ((size_t)r * 64) * 128 + c4);
    f32x4 s = {};
#pragma unroll 16
    for (int lc = 0; lc < 64; ++lc) s += p[lc * 32];     // stride 128 floats
    f32x4 v = *(f32x4*)(state + (size_t)r * 256 + c4);
    v += s;
    *(f32x4*)(state + (size_t)r * 256 + c4) = v;
    __hip_bfloat16 h0 = __float2bfloat16(v[0]), h1 = __float2bfloat16(v[1]);
    __hip_bfloat16 h2 = __float2bfloat16(v[2]), h3 = __float2bfloat16(v[3]);
    uint2 pk;
    pk.x = ((uint32_t)(*(uint16_t*)&h1) << 16) | (uint32_t)(*(uint16_t*)&h0);
    pk.y = ((uint32_t)(*(uint16_t*)&h3) << 16) | (uint32_t)(*(uint16_t*)&h2);
    *(uint2*)(mirror + (size_t)r * 128 + c4) = pk;
}

// ---------------- fused bucket+GEMM phase (v4: XCD swizzle, quad-row gather) ----------------
// Linear grid 512; virt = (bid&7)*64 + bid>>3 so each XCD owns a contiguous lc-range.
// Block (mt, lc): rows [mt*128, +128), labels {2lc, 2lc+1}. 8 waves, 2 blocks/CU.
__global__ __launch_bounds__(512, 4) void fused_phase_kernel(
    const uint16_t* __restrict__ idx,   // [1024][1024] CSR indices (sorted by label)
    const int* __restrict__ off,        // [1024][128] label offsets
    const uint32_t* __restrict__ srcb,  // [1025][64] packed bf16x2 source (row 1024 = zeros)
    const uint16_t* __restrict__ Bt,    // [128][16384] bf16 weights (n-major)
    float* __restrict__ partial)        // [1024][64][128] per-(row,lc) partials
{
    __shared__ uint16_t Atile[128 * 128];        // 32 KiB, 16B-slot XOR-swizzled by row&15
    __shared__ uint16_t Btile[128 * 128];        // 32 KiB, same swizzle
    __shared__ uint16_t sidx[128][48];           // 12 KiB, padded label-pair segments
    __shared__ int rA[128], rB[128], rS0[128], rS1[128], rF[128];   // 2.5 KiB

    const int tid = threadIdx.x;
    const int lane = tid & 63, wv = tid >> 6;
    const int bid = blockIdx.x;
    const int virt = (bid & 7) * 64 + (bid >> 3);   // XCD-chunked (512 = 8*64, bijective)
    const int mt = virt & 7;            // 0..7
    const int lc = virt >> 3;           // 0..63
    const int l0 = lc * 2;
    const int wr = wv >> 2, wc = wv & 3;

    // ---- stage per-row segment info (128 threads, 3 loads each) ----
    if (tid < 128) {
        const int* ro = off + (size_t)(mt * 128 + tid) * 128;
        int s0 = ro[l0];
        int s1 = ro[l0 + 1];
        int s2 = (l0 + 2 < 128) ? ro[l0 + 2] : 1024;
        int len0 = s1 - s0, len1 = s2 - s1;
        int n0 = (len0 + 3) & ~3, n1 = (len1 + 3) & ~3;
        rA[tid] = len0; rB[tid] = len1; rS0[tid] = s0; rS1[tid] = s1;
        rF[tid] = (n0 + n1 > 48);
    }
    __syncthreads();
    // ---- stage indices into LDS, padded to x4 with 1024 (zero row) ----
    {
        int r = tid >> 2, q = tid & 3;
        if (!rF[r]) {
            int len0 = rA[r], len1 = rB[r];
            int n0 = (len0 + 3) & ~3, n1 = (len1 + 3) & ~3;
            const uint16_t* g0 = idx + (size_t)(mt * 128 + r) * 1024 + rS0[r];
            for (int p = q; p < n0; p += 4) sidx[r][p] = (p < len0) ? g0[p] : (uint16_t)1024;
            const uint16_t* g1 = idx + (size_t)(mt * 128 + r) * 1024 + rS1[r];
            for (int p = q; p < n1; p += 4) sidx[r][n0 + p] = (p < len1) ? g1[p] : (uint16_t)1024;
        }
    }
    __syncthreads();

    f32x4 acc[4][2] = {};
    const int brr = lane >> 4;          // 0..3
    const int bx  = lane & 15;          // 16B slot
    const uint32_t lane_u = (uint32_t)lane;

    for (int ls = 0; ls < 2; ++ls) {
        const int l = l0 + ls;

        // ---- B stage: async global_load_lds, inverse-swizzled source ----
#pragma unroll
        for (int g = 0; g < 4; ++g) {
            int row = wv * 16 + g * 4 + brr;
            int sx = bx ^ (row & 15);
            const char* gB = (const char*)Bt + ((size_t)row * 16384 + l * 128 + sx * 8) * 2;
            char* lB = (char*)Btile + (wv * 16 + g * 4) * 256;   // +lane*16 by hardware
            GLD16(gB, lB);
        }

        // ---- A store helper ----
        auto store_a = [&](int jl, float v0, float v1) {
            __hip_bfloat16 h0 = __float2bfloat16(v0), h1 = __float2bfloat16(v1);
            uint32_t pk = ((uint32_t)(*(uint16_t*)&h1) << 16) | (uint32_t)(*(uint16_t*)&h0);
            int phys = (lane >> 2) ^ (jl & 15);
            *(uint32_t*)((char*)Atile + jl * 256 + phys * 16 + (lane & 3) * 4) = pk;
        };
        // ---- slow path (rare): direct-global indices ----
        auto slow_row = [&](int r) {
            int start = ls ? rS1[r] : rS0[r];
            int len   = ls ? rB[r]  : rA[r];
            const uint16_t* ig = idx + (size_t)(mt * 128 + r) * 1024 + start;
            float c0 = 0.f, c1 = 0.f, d0 = 0.f, d1 = 0.f;
            int p = 0;
            for (; p + 3 < len; p += 4) {
                uint32_t v0 = srcb[((uint32_t)ig[p]     << 6) + lane_u];
                uint32_t v1 = srcb[((uint32_t)ig[p + 1] << 6) + lane_u];
                uint32_t v2 = srcb[((uint32_t)ig[p + 2] << 6) + lane_u];
                uint32_t v3 = srcb[((uint32_t)ig[p + 3] << 6) + lane_u];
                c0 += BF_LO(v0) + BF_LO(v1); c1 += BF_HI(v0) + BF_HI(v1);
                d0 += BF_LO(v2) + BF_LO(v3); d1 += BF_HI(v2) + BF_HI(v3);
            }
            for (; p < len; ++p) {
                uint32_t v0 = srcb[((uint32_t)ig[p] << 6) + lane_u];
                c0 += BF_LO(v0); c1 += BF_HI(v0);
            }
            store_a(r, c0 + d0, c1 + d1);
        };

        // ---- gather: each wave owns 16 rows, processed as quads (16 loads in flight) ----
#pragma unroll 1
        for (int jj = 0; jj < 16; jj += 4) {
            int r0 = wv * 16 + jj;
            if (!(rF[r0] | rF[r0 + 1] | rF[r0 + 2] | rF[r0 + 3])) {
                int n_[4], base_[4];
#pragma unroll
                for (int i = 0; i < 4; ++i) {
                    int ri = r0 + i;
                    n_[i]    = ((ls ? rB[ri] : rA[ri]) + 3) & ~3;
                    base_[i] = ls ? ((rA[ri] + 3) & ~3) : 0;
                }
                const uint16_t* i0 = &sidx[r0 + 0][base_[0]];
                const uint16_t* i1 = &sidx[r0 + 1][base_[1]];
                const uint16_t* i2 = &sidx[r0 + 2][base_[2]];
                const uint16_t* i3 = &sidx[r0 + 3][base_[3]];
                float x0 = 0.f, y0 = 0.f, z0 = 0.f, w0 = 0.f;   // row0: (lo,hi) x 2 trees
                float x1 = 0.f, y1 = 0.f, z1 = 0.f, w1 = 0.f;
                float x2 = 0.f, y2 = 0.f, z2 = 0.f, w2 = 0.f;
                float x3 = 0.f, y3 = 0.f, z3 = 0.f, w3 = 0.f;
                int nmax = n_[0];
                if (n_[1] > nmax) nmax = n_[1];
                if (n_[2] > nmax) nmax = n_[2];
                if (n_[3] > nmax) nmax = n_[3];
#pragma unroll 1
                for (int p = 0; p < nmax; p += 4) {
                    if (p < n_[0]) {
                        ushort4 t = *(const ushort4*)(i0 + p);
                        uint32_t v0 = srcb[((uint32_t)t.x << 6) + lane_u];
                        uint32_t v1 = srcb[((uint32_t)t.y << 6) + lane_u];
                        uint32_t v2 = srcb[((uint32_t)t.z << 6) + lane_u];
                        uint32_t v3 = srcb[((uint32_t)t.w << 6) + lane_u];
                        x0 += BF_LO(v0) + BF_LO(v1); y0 += BF_HI(v0) + BF_HI(v1);
                        z0 += BF_LO(v2) + BF_LO(v3); w0 += BF_HI(v2) + BF_HI(v3);
                    }
                    if (p < n_[1]) {
                        ushort4 t = *(const ushort4*)(i1 + p);
                        uint32_t v0 = srcb[((uint32_t)t.x << 6) + lane_u];
                        uint32_t v1 = srcb[((uint32_t)t.y << 6) + lane_u];
                        uint32_t v2 = srcb[((uint32_t)t.z << 6) + lane_u];
                        uint32_t v3 = srcb[((uint32_t)t.w << 6) + lane_u];
                        x1 += BF_LO(v0) + BF_LO(v1); y1 += BF_HI(v0) + BF_HI(v1);
                        z1 += BF_LO(v2) + BF_LO(v3); w1 += BF_HI(v2) + BF_HI(v3);
                    }
                    if (p < n_[2]) {
                        ushort4 t = *(const ushort4*)(i2 + p);
                        uint32_t v0 = srcb[((uint32_t)t.x << 6) + lane_u];
                        uint32_t v1 = srcb[((uint32_t)t.y << 6) + lane_u];
                        uint32_t v2 = srcb[((uint32_t)t.z << 6) + lane_u];
                        uint32_t v3 = srcb[((uint32_t)t.w << 6) + lane_u];
                        x2 += BF_LO(v0) + BF_LO(v1); y2 += BF_HI(v0) + BF_HI(v1);
                        z2 += BF_LO(v2) + BF_LO(v3); w2 += BF_HI(v2) + BF_HI(v3);
                    }
                    if (p < n_[3]) {
                        ushort4 t = *(const ushort4*)(i3 + p);
                        uint32_t v0 = srcb[((uint32_t)t.x << 6) + lane_u];
                        uint32_t v1 = srcb[((uint32_t)t.y << 6) + lane_u];
                        uint32_t v2 = srcb[((uint32_t)t.z << 6) + lane_u];
                        uint32_t v3 = srcb[((uint32_t)t.w << 6) + lane_u];
                        x3 += BF_LO(v0) + BF_LO(v1); y3 += BF_HI(v0) + BF_HI(v1);
                        z3 += BF_LO(v2) + BF_LO(v3); w3 += BF_HI(v2) + BF_HI(v3);
                    }
                }
                store_a(r0 + 0, x0 + z0, y0 + w0);
                store_a(r0 + 1, x1 + z1, y1 + w1);
                store_a(r0 + 2, x2 + z2, y2 + w2);
                store_a(r0 + 3, x3 + z3, y3 + w3);
            } else {
                slow_row(r0); slow_row(r0 + 1); slow_row(r0 + 2); slow_row(r0 + 3);
            }
        }
        __syncthreads();   // drains GLD16 vmcnt + orders LDS writes

        // ---- MFMA: wave tile 64x32, K=128 ----
        {
            const int q = lane >> 4, rl = lane & 15;
#pragma unroll
            for (int kk = 0; kk < 4; ++kk) {
                bf16x8 af[4], bfr[2];
#pragma unroll
                for (int m = 0; m < 4; ++m) {
                    int row = wr * 64 + m * 16 + rl;
                    int sw = (kk * 4 + q) ^ (row & 15);
                    af[m] = *(const bf16x8*)((const char*)Atile + row * 256 + sw * 16);
                }
#pragma unroll
                for (int n = 0; n < 2; ++n) {
                    int row = wc * 32 + n * 16 + rl;
                    int sw = (kk * 4 + q) ^ (row & 15);
                    bfr[n] = *(const bf16x8*)((const char*)Btile + row * 256 + sw * 16);
                }
#pragma unroll
                for (int m = 0; m < 4; ++m)
#pragma unroll
                    for (int n = 0; n < 2; ++n)
                        acc[m][n] = __builtin_amdgcn_mfma_f32_16x16x32_bf16(af[m], bfr[n], acc[m][n], 0, 0, 0);
            }
        }
        __syncthreads();   // before next label overwrites A/B tiles
    }

    // ---- epilogue: plain stores to private partial slice (no atomics) ----
    const int rq = lane >> 4, cn = lane & 15;
#pragma unroll
    for (int m = 0; m < 4; ++m)
#pragma unroll
        for (int n = 0; n < 2; ++n)
#pragma unroll
            for (int r = 0; r < 4; ++r) {
                int row = mt * 128 + wr * 64 + m * 16 + rq * 4 + r;
                int col = wc * 32 + n * 16 + cn;
                partial[((size_t)row * 64 + lc) * 128 + col] = acc[m][n][r];
            }
}

extern "C" void kernel_launch(void* const* d_in, const int* in_sizes, int n_in,
                              void* d_out, int out_size, void* d_ws, size_t ws_size,
                              hipStream_t stream) {
    const int*   inputs  = (const int*)d_in[0];
    const float* first_a = (const float*)d_in[1];
    const float* first_t = (const float*)d_in[2];
    const float* Awij    = (const float*)d_in[3];
    const float* Awij2   = (const float*)d_in[4];
    float* out = (float*)d_out;

    // workspace layout (50 MiB total)
    char* w = (char*)d_ws;
    int*      inputsT = (int*)(w);                      // 4 MiB (prep-only)
    uint16_t* BtA     = (uint16_t*)(w + (4u << 20));    // 4 MiB  [a][l*128+e] = Awij2[l][e][a]
    uint16_t* BtT     = (uint16_t*)(w + (8u << 20));    // 4 MiB  [e][l*128+a] = Awij[l][a][e]
    uint16_t* idxA    = (uint16_t*)(w + (12u << 20));   // 2 MiB
    uint16_t* idxT    = (uint16_t*)(w + (14u << 20));   // 2 MiB
    int*      offA    = (int*)(w + (16u << 20));        // 512 KiB
    int*      offT    = (int*)(w + (16u << 20) + (1u << 19)); // 512 KiB
    uint16_t* srcAb   = (uint16_t*)(w + (17u << 20));   // [1025][128] bf16
    uint16_t* srcTb   = (uint16_t*)(w + (17u << 20) + (384u << 10)); // [1025][128] bf16
    float*    partial = (float*)(w + (18u << 20));      // 32 MiB  [1024][64][128] f32
    if (ws_size < (50u << 20)) return;

    float* stateA = out;                 // [1024][256], cols 0..127 live
    float* stateT = out + 1024 * 256;    // [1024][256], cols 0..127 live

    transpose_int_kernel<<<1024, 256, 0, stream>>>(inputs, inputsT);
    transpose_w_kernel<<<4096, 256, 0, stream>>>(Awij2, Awij, BtA, BtT);
    csr_build_kernel<<<2048, 128, 0, stream>>>(inputs, inputsT, idxA, idxT, offA, offT);
    init_out_kernel<<<2048, 256, 0, stream>>>(first_a, first_t, out, srcAb, srcTb);

    for (int s = 0; s < 2; ++s) {
        // Phase A: a += bucket_t(update_t) x Awij2
        fused_phase_kernel<<<512, 512, 0, stream>>>(idxA, offA, (const uint32_t*)srcTb, BtA, partial);
        reduce_mirror_kernel<<<128, 256, 0, stream>>>(partial, stateA, srcAb);
        // Phase T: t += bucket_j(new_a) x Awij
        fused_phase_kernel<<<512, 512, 0, stream>>>(idxT, offT, (const uint32_t*)srcAb, BtT, partial);
        reduce_mirror_kernel<<<128, 256, 0, stream>>>(partial, stateT, srcTb);
    }
}

// Round 9
// 233.720 us; speedup vs baseline: 1.0120x; 1.0120x over previous
//
#include <hip/hip_runtime.h>
#include <hip/hip_bf16.h>
#include <stdint.h>

// Problem constants: NA=NT=1024, A_DIM=E_DIM=128, L=128, K = L*128 = 16384

typedef short bf16x8 __attribute__((ext_vector_type(8)));
typedef float f32x4  __attribute__((ext_vector_type(4)));

#define GLD16(g, l) __builtin_amdgcn_global_load_lds( \
    (const __attribute__((address_space(1))) void*)(uintptr_t)(g), \
    (__attribute__((address_space(3))) void*)(uintptr_t)(l), 16, 0, 0)

#define BF_LO(v) __uint_as_float((v) << 16)
#define BF_HI(v) __uint_as_float((v) & 0xffff0000u)

// ---------------- prep: transpose inputs [1024][1024] -> inputsT ----------------
__global__ __launch_bounds__(256) void transpose_int_kernel(const int* __restrict__ in,
                                                            int* __restrict__ out) {
    __shared__ int tile[32][33];
    int b = blockIdx.x;              // 1024 tiles
    int tr = b >> 5, tc = b & 31;
    int r0 = tr * 32, c0 = tc * 32;
    int tx = threadIdx.x & 31, ty = threadIdx.x >> 5;
#pragma unroll
    for (int p = 0; p < 4; ++p)
        tile[ty + p * 8][tx] = in[(size_t)(r0 + ty + p * 8) * 1024 + c0 + tx];
    __syncthreads();
#pragma unroll
    for (int p = 0; p < 4; ++p) {
        int cc = ty + p * 8;
        out[(size_t)(c0 + cc) * 1024 + r0 + tx] = tile[tx][cc];
    }
}

// ------------- prep: transpose+cast weights f32 [16384][128] -> bf16 [128][16384] -------------
__global__ __launch_bounds__(256) void transpose_w_kernel(const float* __restrict__ W0,
                                                          const float* __restrict__ W1,
                                                          uint16_t* __restrict__ O0,
                                                          uint16_t* __restrict__ O1) {
    __shared__ float tile[32][33];
    int b = blockIdx.x;              // 4096 tiles (2048 per weight)
    const float* W = W0;
    uint16_t* O = O0;
    if (b >= 2048) { b -= 2048; W = W1; O = O1; }
    int tr = b >> 2, tc = b & 3;
    int r0 = tr * 32, c0 = tc * 32;
    int tx = threadIdx.x & 31, ty = threadIdx.x >> 5;
#pragma unroll
    for (int p = 0; p < 4; ++p)
        tile[ty + p * 8][tx] = W[(size_t)(r0 + ty + p * 8) * 128 + c0 + tx];
    __syncthreads();
#pragma unroll
    for (int p = 0; p < 4; ++p) {
        int cc = ty + p * 8;
        __hip_bfloat16 h = __float2bfloat16(tile[tx][cc]);
        O[(size_t)(c0 + cc) * 16384 + r0 + tx] = *(uint16_t*)&h;
    }
}

// ---------------- prep: CSR build — parallel deterministic counting sort ----------------
__global__ __launch_bounds__(128) void csr_build_kernel(const int* __restrict__ inA,
                                                        const int* __restrict__ inT,
                                                        uint16_t* __restrict__ idxA,
                                                        uint16_t* __restrict__ idxT,
                                                        int* __restrict__ offA,
                                                        int* __restrict__ offT) {
    __shared__ uint16_t chist[128][128];  // 32 KiB [chunk][label]
    __shared__ int lab[1024];
    __shared__ int tot[128];
    __shared__ int off[128];
    int b = blockIdx.x;
    const int* in = inA; uint16_t* idx = idxA; int* offo = offA; int row = b;
    if (b >= 1024) { in = inT; idx = idxT; offo = offT; row = b - 1024; }
    const int c = threadIdx.x;            // 0..127

    for (int i = c; i < 8192; i += 128) ((uint32_t*)chist)[i] = 0;
    for (int i = c; i < 1024; i += 128) lab[i] = in[(size_t)row * 1024 + i];
    __syncthreads();

    int mylab[8], rloc[8];
#pragma unroll
    for (int k = 0; k < 8; ++k) {
        int l = lab[c * 8 + k];
        mylab[k] = l;
        rloc[k] = chist[c][l];
        chist[c][l] = (uint16_t)(rloc[k] + 1);
    }
    __syncthreads();

    {   // column prefix over chunks: thread c owns label l=c
        int run = 0;
#pragma unroll 4
        for (int ch = 0; ch < 128; ++ch) {
            int v = chist[ch][c];
            chist[ch][c] = (uint16_t)run;
            run += v;
        }
        tot[c] = run;
    }
    __syncthreads();
    if (c == 0) {
        int s = 0;
#pragma unroll 4
        for (int l = 0; l < 128; ++l) { off[l] = s; s += tot[l]; }
    }
    __syncthreads();
    offo[(size_t)row * 128 + c] = off[c];
#pragma unroll
    for (int k = 0; k < 8; ++k) {
        int l = mylab[k];
        int pos = off[l] + (int)chist[c][l] + rloc[k];
        idx[(size_t)row * 1024 + pos] = (uint16_t)(c * 8 + k);
    }
}

// ---------------- prep: init output + bf16 mirrors (incl. zero row 1024) ----------------
__global__ __launch_bounds__(256) void init_out_kernel(const float* __restrict__ fa,
                                                       const float* __restrict__ ft,
                                                       float* __restrict__ out,
                                                       uint16_t* __restrict__ srcAb,
                                                       uint16_t* __restrict__ srcTb) {
    int i = blockIdx.x * 256 + threadIdx.x;   // grid 2048 -> 524288
    int r = i >> 8, c = i & 255;
    float v = 0.f;
    if (c < 128) {
        v = (r < 1024) ? fa[(size_t)r * 128 + c] : ft[(size_t)(r - 1024) * 128 + c];
        __hip_bfloat16 h = __float2bfloat16(v);
        if (r < 1024) srcAb[(size_t)r * 128 + c] = *(uint16_t*)&h;
        else          srcTb[(size_t)(r - 1024) * 128 + c] = *(uint16_t*)&h;
    }
    out[i] = v;
    if (i < 64) {   // dummy zero row (index 1024) used for segment padding
        ((uint32_t*)(srcAb + 1024 * 128))[i] = 0;
        ((uint32_t*)(srcTb + 1024 * 128))[i] = 0;
    }
}

// ---------------- bucket: U[j, l*128+e] = sum_{t in list(j,l)} src[t][e] ----------------
// 1 block per j, 8 waves, 16 labels/wave in interleaved pairs. Tiny LDS -> 4 blocks/CU.
__global__ __launch_bounds__(512, 8) void bucket_kernel(
    const uint16_t* __restrict__ idx,   // [1024][1024] CSR indices
    const int* __restrict__ off,        // [1024][128]
    const uint32_t* __restrict__ srcb,  // [1025][64] packed bf16x2 (row 1024 = zeros)
    uint32_t* __restrict__ U32)         // [1024][8192]
{
    __shared__ uint16_t sidxp[128][44];  // 11 KiB padded segments
    __shared__ int soff[129];
    __shared__ int slen[128];            // padded len, or -1 overflow
    const int j = blockIdx.x;
    const int tid = threadIdx.x;
    const int lane = tid & 63, wv = tid >> 6;
    const uint32_t lane_u = (uint32_t)lane;

    if (tid < 128) soff[tid] = off[(size_t)j * 128 + tid];
    if (tid == 0) soff[128] = 1024;
    __syncthreads();
    {
        int l = tid >> 2, q = tid & 3;
        int s = soff[l], e = soff[l + 1];
        int len = e - s;
        int n = (len + 3) & ~3;
        if (q == 0) slen[l] = (n <= 44) ? n : -1;
        if (n <= 44) {
            const uint16_t* g = idx + (size_t)j * 1024 + s;
            for (int p = q; p < n; p += 4) sidxp[l][p] = (p < len) ? g[p] : (uint16_t)1024;
        }
    }
    __syncthreads();

    // slow fallback for overflow labels (essentially never taken)
    auto slow_one = [&](int l, float& r0, float& r1) {
        int s = soff[l], len = soff[l + 1] - s;
        const uint16_t* ig = idx + (size_t)j * 1024 + s;
        float p0 = 0.f, p1 = 0.f, q0 = 0.f, q1 = 0.f;
        int p = 0;
        for (; p + 3 < len; p += 4) {
            uint32_t v0 = srcb[((uint32_t)ig[p]     << 6) + lane_u];
            uint32_t v1 = srcb[((uint32_t)ig[p + 1] << 6) + lane_u];
            uint32_t v2 = srcb[((uint32_t)ig[p + 2] << 6) + lane_u];
            uint32_t v3 = srcb[((uint32_t)ig[p + 3] << 6) + lane_u];
            p0 += BF_LO(v0) + BF_LO(v1); p1 += BF_HI(v0) + BF_HI(v1);
            q0 += BF_LO(v2) + BF_LO(v3); q1 += BF_HI(v2) + BF_HI(v3);
        }
        for (; p < len; ++p) {
            uint32_t v0 = srcb[((uint32_t)ig[p] << 6) + lane_u];
            p0 += BF_LO(v0); p1 += BF_HI(v0);
        }
        r0 = p0 + q0; r1 = p1 + q1;
    };

#pragma unroll 1
    for (int lp = 0; lp < 16; lp += 2) {
        int la = wv * 16 + lp, lb = la + 1;
        int na = slen[la], nb = slen[lb];
        float ra0, ra1, rb0, rb1;
        if ((na | nb) >= 0) {
            const uint16_t* iA = &sidxp[la][0];
            const uint16_t* iB = &sidxp[lb][0];
            float a0 = 0.f, a1 = 0.f, b0 = 0.f, b1 = 0.f;
            float c0 = 0.f, c1 = 0.f, d0 = 0.f, d1 = 0.f;
            int nmax = na > nb ? na : nb;
#pragma unroll 1
            for (int p = 0; p < nmax; p += 4) {
                if (p < na) {
                    ushort4 t = *(const ushort4*)(iA + p);   // one ds_read_b64
                    uint32_t v0 = srcb[((uint32_t)t.x << 6) + lane_u];
                    uint32_t v1 = srcb[((uint32_t)t.y << 6) + lane_u];
                    uint32_t v2 = srcb[((uint32_t)t.z << 6) + lane_u];
                    uint32_t v3 = srcb[((uint32_t)t.w << 6) + lane_u];
                    a0 += BF_LO(v0) + BF_LO(v1); a1 += BF_HI(v0) + BF_HI(v1);
                    b0 += BF_LO(v2) + BF_LO(v3); b1 += BF_HI(v2) + BF_HI(v3);
                }
                if (p < nb) {
                    ushort4 t = *(const ushort4*)(iB + p);
                    uint32_t v0 = srcb[((uint32_t)t.x << 6) + lane_u];
                    uint32_t v1 = srcb[((uint32_t)t.y << 6) + lane_u];
                    uint32_t v2 = srcb[((uint32_t)t.z << 6) + lane_u];
                    uint32_t v3 = srcb[((uint32_t)t.w << 6) + lane_u];
                    c0 += BF_LO(v0) + BF_LO(v1); c1 += BF_HI(v0) + BF_HI(v1);
                    d0 += BF_LO(v2) + BF_LO(v3); d1 += BF_HI(v2) + BF_HI(v3);
                }
            }
            ra0 = a0 + b0; ra1 = a1 + b1;
            rb0 = c0 + d0; rb1 = c1 + d1;
        } else {
            slow_one(la, ra0, ra1);
            slow_one(lb, rb0, rb1);
        }
        __hip_bfloat16 h0 = __float2bfloat16(ra0), h1 = __float2bfloat16(ra1);
        U32[(size_t)j * 8192 + la * 64 + lane] =
            ((uint32_t)(*(uint16_t*)&h1) << 16) | (uint32_t)(*(uint16_t*)&h0);
        __hip_bfloat16 h2 = __float2bfloat16(rb0), h3 = __float2bfloat16(rb1);
        U32[(size_t)j * 8192 + lb * 64 + lane] =
            ((uint32_t)(*(uint16_t*)&h3) << 16) | (uint32_t)(*(uint16_t*)&h2);
    }
}

// ---------------- GEMM: partial[1024][32][128] = A[1024][16384] x Bt[128][16384]^T ----------------
// grid (8 mt, 32 kc), 512 thr = 8 waves (2x4), wave tile 64x32, K=512/block, no atomics.
__global__ __launch_bounds__(512) void gemm_kernel(const uint16_t* __restrict__ A,
                                                   const uint16_t* __restrict__ Bt,
                                                   float* __restrict__ partial) {
    __shared__ uint16_t Atile[128 * 64];   // 16 KiB, XOR-swizzled 16B slots
    __shared__ uint16_t Btile[128 * 64];

    const int tid = threadIdx.x;
    const int lane = tid & 63;
    const int wid = tid >> 6;
    const int wr = wid >> 2, wc = wid & 3;
    const int mbase = blockIdx.x * 128;
    const int kc = blockIdx.y;
    const size_t kchunk = (size_t)kc * 512;

    f32x4 acc[4][2] = {};
    const int rlane = lane >> 3;
    const int slane = lane & 7;

    for (int it = 0; it < 8; ++it) {
        const size_t kb2 = (kchunk + (size_t)it * 64) * 2;
#pragma unroll
        for (int c = 0; c < 2; ++c) {
            int r = c * 64 + wid * 8 + rlane;
            int col16 = slane ^ (r & 7);                     // pre-swizzled source (involution)
            const char* gA = (const char*)A + (size_t)(mbase + r) * 32768 + kb2 + col16 * 16;
            char* lA = (char*)Atile + c * 8192 + wid * 1024; // wave-uniform linear dest
            GLD16(gA, lA);
            const char* gB = (const char*)Bt + (size_t)r * 32768 + kb2 + col16 * 16;
            char* lB = (char*)Btile + c * 8192 + wid * 1024;
            GLD16(gB, lB);
        }
        __syncthreads();

        const int q = lane >> 4, rl = lane & 15;
#pragma unroll
        for (int kk = 0; kk < 2; ++kk) {
            bf16x8 af[4], bfr[2];
#pragma unroll
            for (int m = 0; m < 4; ++m) {
                int row = wr * 64 + m * 16 + rl;
                int sw = (kk * 4 + q) ^ (row & 7);
                af[m] = *(const bf16x8*)((const char*)Atile + row * 128 + sw * 16);
            }
#pragma unroll
            for (int n = 0; n < 2; ++n) {
                int row = wc * 32 + n * 16 + rl;
                int sw = (kk * 4 + q) ^ (row & 7);
                bfr[n] = *(const bf16x8*)((const char*)Btile + row * 128 + sw * 16);
            }
#pragma unroll
            for (int m = 0; m < 4; ++m)
#pragma unroll
                for (int n = 0; n < 2; ++n)
                    acc[m][n] = __builtin_amdgcn_mfma_f32_16x16x32_bf16(af[m], bfr[n], acc[m][n], 0, 0, 0);
        }
        __syncthreads();
    }

    const int rq = lane >> 4, cn = lane & 15;   // C/D: col=lane&15, row=(lane>>4)*4+reg
#pragma unroll
    for (int m = 0; m < 4; ++m)
#pragma unroll
        for (int n = 0; n < 2; ++n)
#pragma unroll
            for (int r = 0; r < 4; ++r) {
                int row = mbase + wr * 64 + m * 16 + rq * 4 + r;
                int col = wc * 32 + n * 16 + cn;
                partial[((size_t)row * 32 + kc) * 128 + col] = acc[m][n][r];
            }
}

// ---------------- reduce 32 partials + update state + emit bf16 mirror ----------------
__global__ __launch_bounds__(256) void reduce_mirror_kernel(const float* __restrict__ partial,
                                                            float* __restrict__ state,
                                                            uint16_t* __restrict__ mirror) {
    const int r = blockIdx.x * 8 + (threadIdx.x >> 5);   // grid 128 -> rows 0..1023
    const int c4 = (threadIdx.x & 31) * 4;               // col group of 4
    const f32x4* p = (const f32x4*)(partial + (size_t)r * 32 * 128 + c4);
    f32x4 s = {};
#pragma unroll 8
    for (int kc = 0; kc < 32; ++kc) s += p[kc * 32];     // stride 128 floats
    f32x4 v = *(f32x4*)(state + (size_t)r * 256 + c4);
    v += s;
    *(f32x4*)(state + (size_t)r * 256 + c4) = v;
    __hip_bfloat16 h0 = __float2bfloat16(v[0]), h1 = __float2bfloat16(v[1]);
    __hip_bfloat16 h2 = __float2bfloat16(v[2]), h3 = __float2bfloat16(v[3]);
    uint2 pk;
    pk.x = ((uint32_t)(*(uint16_t*)&h1) << 16) | (uint32_t)(*(uint16_t*)&h0);
    pk.y = ((uint32_t)(*(uint16_t*)&h3) << 16) | (uint32_t)(*(uint16_t*)&h2);
    *(uint2*)(mirror + (size_t)r * 128 + c4) = pk;
}

extern "C" void kernel_launch(void* const* d_in, const int* in_sizes, int n_in,
                              void* d_out, int out_size, void* d_ws, size_t ws_size,
                              hipStream_t stream) {
    const int*   inputs  = (const int*)d_in[0];
    const float* first_a = (const float*)d_in[1];
    const float* first_t = (const float*)d_in[2];
    const float* Awij    = (const float*)d_in[3];
    const float* Awij2   = (const float*)d_in[4];
    float* out = (float*)d_out;

    // workspace layout (66 MiB total; d_ws is 256 MiB)
    char* w = (char*)d_ws;
    int*      inputsT = (int*)(w);                      // 4 MiB (prep-only)
    uint16_t* BtA     = (uint16_t*)(w + (4u << 20));    // 4 MiB  [a][l*128+e] = Awij2[l][e][a]
    uint16_t* BtT     = (uint16_t*)(w + (8u << 20));    // 4 MiB  [e][l*128+a] = Awij[l][a][e]
    uint16_t* idxA    = (uint16_t*)(w + (12u << 20));   // 2 MiB
    uint16_t* idxT    = (uint16_t*)(w + (14u << 20));   // 2 MiB
    int*      offA    = (int*)(w + (16u << 20));        // 512 KiB
    int*      offT    = (int*)(w + (16u << 20) + (1u << 19)); // 512 KiB
    uint16_t* srcAb   = (uint16_t*)(w + (17u << 20));   // [1025][128] bf16
    uint16_t* srcTb   = (uint16_t*)(w + (17u << 20) + (384u << 10)); // [1025][128] bf16
    uint16_t* U       = (uint16_t*)(w + (18u << 20));   // 32 MiB  [1024][16384] bf16
    float*    partial = (float*)(w + (50u << 20));      // 16 MiB  [1024][32][128] f32
    if (ws_size < (66u << 20)) return;

    float* stateA = out;                 // [1024][256], cols 0..127 live
    float* stateT = out + 1024 * 256;    // [1024][256], cols 0..127 live

    transpose_int_kernel<<<1024, 256, 0, stream>>>(inputs, inputsT);
    transpose_w_kernel<<<4096, 256, 0, stream>>>(Awij2, Awij, BtA, BtT);
    csr_build_kernel<<<2048, 128, 0, stream>>>(inputs, inputsT, idxA, idxT, offA, offT);
    init_out_kernel<<<2048, 256, 0, stream>>>(first_a, first_t, out, srcAb, srcTb);

    for (int s = 0; s < 2; ++s) {
        // Phase A: a += bucket_t(update_t) x Awij2
        bucket_kernel<<<1024, 512, 0, stream>>>(idxA, offA, (const uint32_t*)srcTb, (uint32_t*)U);
        gemm_kernel<<<dim3(8, 32), 512, 0, stream>>>(U, BtA, partial);
        reduce_mirror_kernel<<<128, 256, 0, stream>>>(partial, stateA, srcAb);
        // Phase T: t += bucket_j(new_a) x Awij
        bucket_kernel<<<1024, 512, 0, stream>>>(idxT, offT, (const uint32_t*)srcAb, (uint32_t*)U);
        gemm_kernel<<<dim3(8, 32), 512, 0, stream>>>(U, BtT, partial);
        reduce_mirror_kernel<<<128, 256, 0, stream>>>(partial, stateT, srcTb);
    }
}

// Round 10
// 197.143 us; speedup vs baseline: 1.1998x; 1.1855x over previous
//
#include <hip/hip_runtime.h>
#include <hip/hip_bf16.h>
#include <stdint.h>

// Problem constants: NA=NT=1024, A_DIM=E_DIM=128, L=128

typedef short bf16x8 __attribute__((ext_vector_type(8)));
typedef float f32x4  __attribute__((ext_vector_type(4)));

#define GLD16(g, l) __builtin_amdgcn_global_load_lds( \
    (const __attribute__((address_space(1))) void*)(uintptr_t)(g), \
    (__attribute__((address_space(3))) void*)(uintptr_t)(l), 16, 0, 0)

#define BF_LO(v) __uint_as_float((v) << 16)
#define BF_HI(v) __uint_as_float((v) & 0xffff0000u)

static __device__ __forceinline__ uint32_t pk2(float lo, float hi) {
    __hip_bfloat16 h0 = __float2bfloat16(lo), h1 = __float2bfloat16(hi);
    return ((uint32_t)(*(uint16_t*)&h1) << 16) | (uint32_t)(*(uint16_t*)&h0);
}

// ---------------- prep: transpose inputs [1024][1024] -> inputsT ----------------
__global__ __launch_bounds__(256) void transpose_int_kernel(const int* __restrict__ in,
                                                            int* __restrict__ out) {
    __shared__ int tile[32][33];
    int b = blockIdx.x;              // 1024 tiles
    int tr = b >> 5, tc = b & 31;
    int r0 = tr * 32, c0 = tc * 32;
    int tx = threadIdx.x & 31, ty = threadIdx.x >> 5;
#pragma unroll
    for (int p = 0; p < 4; ++p)
        tile[ty + p * 8][tx] = in[(size_t)(r0 + ty + p * 8) * 1024 + c0 + tx];
    __syncthreads();
#pragma unroll
    for (int p = 0; p < 4; ++p) {
        int cc = ty + p * 8;
        out[(size_t)(c0 + cc) * 1024 + r0 + tx] = tile[tx][cc];
    }
}

// ------- prep: per-label 128x128 transpose + bf16 cast -------
// W2T[(l*128+a)][e] = Awij2[l][e][a]   (for phase A: t_proj[t,(l,a)] = sum_e t[t,e]*Awij2[l,e,a])
// W1T[(l*128+e)][a] = Awij [l][a][e]   (for phase T)
__global__ __launch_bounds__(256) void transpose_w_kernel(const float* __restrict__ W2,
                                                          const float* __restrict__ W1,
                                                          uint16_t* __restrict__ O2T,
                                                          uint16_t* __restrict__ O1T) {
    __shared__ float tile[32][33];
    int b = blockIdx.x;              // 4096 = 2 weights x 128 l x 16 subtiles
    const float* W = W2;
    uint16_t* O = O2T;
    if (b >= 2048) { b -= 2048; W = W1; O = O1T; }
    int l = b >> 4, sub = b & 15;
    int x0 = (sub >> 2) * 32, y0 = (sub & 3) * 32;   // src[l][x][y], 128x128
    int tx = threadIdx.x & 31, ty = threadIdx.x >> 5;
#pragma unroll
    for (int p = 0; p < 4; ++p)
        tile[ty + p * 8][tx] = W[(size_t)l * 16384 + (size_t)(x0 + ty + p * 8) * 128 + y0 + tx];
    __syncthreads();
#pragma unroll
    for (int p = 0; p < 4; ++p) {
        int yy = ty + p * 8;
        __hip_bfloat16 h = __float2bfloat16(tile[tx][yy]);   // dst[y][x] = src[x][y]
        O[(size_t)(l * 128 + y0 + yy) * 128 + x0 + tx] = *(uint16_t*)&h;
    }
}

// ---------------- prep: init output + bf16 mirrors ----------------
__global__ __launch_bounds__(256) void init_out_kernel(const float* __restrict__ fa,
                                                       const float* __restrict__ ft,
                                                       float* __restrict__ out,
                                                       uint16_t* __restrict__ srcAb,
                                                       uint16_t* __restrict__ srcTb) {
    int i = blockIdx.x * 256 + threadIdx.x;   // grid 2048 -> 524288
    int r = i >> 8, c = i & 255;
    float v = 0.f;
    if (c < 128) {
        v = (r < 1024) ? fa[(size_t)r * 128 + c] : ft[(size_t)(r - 1024) * 128 + c];
        __hip_bfloat16 h = __float2bfloat16(v);
        if (r < 1024) srcAb[(size_t)r * 128 + c] = *(uint16_t*)&h;
        else          srcTb[(size_t)(r - 1024) * 128 + c] = *(uint16_t*)&h;
    }
    out[i] = v;
}

// ---------------- proj: P[1024][16384] = src[1024][128] x WT[16384][128]^T (bf16, K=128) ----------------
// grid 1024 linear, XCD-chunked: nt-ranges per XCD so WT slices fetched once per XCD.
// 8 waves (2x4), wave tile 64x32, swapped-operand MFMA -> C^T fragments (regs = 4 consecutive cols).
__global__ __launch_bounds__(512, 2) void proj_kernel(const uint16_t* __restrict__ src,  // [1024][128]
                                                      const uint16_t* __restrict__ WT,   // [16384][128]
                                                      uint16_t* __restrict__ proj) {     // [1024][16384]
    __shared__ uint16_t At[128 * 128];   // 32 KiB, 16B-slot XOR-swizzled by row&15
    __shared__ uint16_t Bt[128 * 128];

    const int tid = threadIdx.x;
    const int lane = tid & 63, wv = tid >> 6;
    const int bid = blockIdx.x;
    const int virt = (bid & 7) * 128 + (bid >> 3);   // bijective, 8 XCD chunks
    const int mt = virt & 7;            // 0..7
    const int nt = virt >> 3;           // 0..127
    const int wr = wv >> 2, wc = wv & 3;

    const int rr = lane >> 4;           // 0..3
    const int sx16 = lane & 15;
#pragma unroll
    for (int g = 0; g < 4; ++g) {
        int row = wv * 16 + g * 4 + rr;
        int sx = sx16 ^ (row & 15);     // pre-swizzled source (involution)
        GLD16((const char*)src + ((size_t)(mt * 128 + row) * 128 + sx * 8) * 2,
              (char*)At + (wv * 16 + g * 4) * 256);
        GLD16((const char*)WT + ((size_t)(nt * 128 + row) * 128 + sx * 8) * 2,
              (char*)Bt + (wv * 16 + g * 4) * 256);
    }
    __syncthreads();   // drains GLD16 vmcnt

    f32x4 acc[4][2] = {};
    const int q = lane >> 4, rl = lane & 15;
#pragma unroll
    for (int kk = 0; kk < 4; ++kk) {
        bf16x8 af[4], bfr[2];
#pragma unroll
        for (int m = 0; m < 4; ++m) {
            int row = wr * 64 + m * 16 + rl;
            int sw = (kk * 4 + q) ^ (row & 15);
            af[m] = *(const bf16x8*)((const char*)At + row * 256 + sw * 16);
        }
#pragma unroll
        for (int n = 0; n < 2; ++n) {
            int row = wc * 32 + n * 16 + rl;
            int sw = (kk * 4 + q) ^ (row & 15);
            bfr[n] = *(const bf16x8*)((const char*)Bt + row * 256 + sw * 16);
        }
#pragma unroll
        for (int m = 0; m < 4; ++m)
#pragma unroll
            for (int n = 0; n < 2; ++n)   // swapped operands -> D = C^T fragment
                acc[m][n] = __builtin_amdgcn_mfma_f32_16x16x32_bf16(bfr[n], af[m], acc[m][n], 0, 0, 0);
    }

    // C^T frag: col(lane&15) = m-space, row(q*4+reg) = n-space -> regs are 4 consecutive n.
#pragma unroll
    for (int m = 0; m < 4; ++m)
#pragma unroll
        for (int n = 0; n < 2; ++n) {
            int mrow = mt * 128 + wr * 64 + m * 16 + rl;
            int ncol = nt * 128 + wc * 32 + n * 16 + q * 4;
            uint2 pk;
            pk.x = pk2(acc[m][n][0], acc[m][n][1]);
            pk.y = pk2(acc[m][n][2], acc[m][n][3]);
            *(uint2*)(proj + (size_t)mrow * 16384 + ncol) = pk;
        }
}

// ---------------- gather: state[j] += sum_t proj[t, lab[j][t], :]; emit bf16 mirror ----------------
// 1 block per j, 8 waves x 128 edges, lane covers channels (2lane, 2lane+1). No CSR needed.
__global__ __launch_bounds__(512, 8) void gather_kernel(const int* __restrict__ labels,   // [1024][1024]
                                                        const uint32_t* __restrict__ proj, // u32 view
                                                        float* __restrict__ state,         // stride 256
                                                        uint16_t* __restrict__ mirror) {   // [1024][128]
    __shared__ uint16_t lab16[1024];
    __shared__ float red[8][128];
    const int j = blockIdx.x;
    const int tid = threadIdx.x;
    const int lane = tid & 63, wv = tid >> 6;

    lab16[tid] = (uint16_t)labels[(size_t)j * 1024 + tid];
    lab16[512 + tid] = (uint16_t)labels[(size_t)j * 1024 + 512 + tid];
    __syncthreads();

    float a0 = 0.f, a1 = 0.f, b0 = 0.f, b1 = 0.f;
    const uint32_t lane_u = (uint32_t)lane;
#pragma unroll 1
    for (int i = 0; i < 128; i += 8) {
        int t = wv * 128 + i;
        ushort4 L0 = *(const ushort4*)&lab16[t];       // 2x ds_read_b64
        ushort4 L1 = *(const ushort4*)&lab16[t + 4];
        const uint32_t* base = proj + (size_t)t * 8192 + lane_u;
        uint32_t v0 = base[(uint32_t)L0.x * 64];
        uint32_t v1 = base[8192u + (uint32_t)L0.y * 64];
        uint32_t v2 = base[16384u + (uint32_t)L0.z * 64];
        uint32_t v3 = base[24576u + (uint32_t)L0.w * 64];
        uint32_t v4 = base[32768u + (uint32_t)L1.x * 64];
        uint32_t v5 = base[40960u + (uint32_t)L1.y * 64];
        uint32_t v6 = base[49152u + (uint32_t)L1.z * 64];
        uint32_t v7 = base[57344u + (uint32_t)L1.w * 64];
        a0 += BF_LO(v0) + BF_LO(v1) + BF_LO(v2) + BF_LO(v3);
        a1 += BF_HI(v0) + BF_HI(v1) + BF_HI(v2) + BF_HI(v3);
        b0 += BF_LO(v4) + BF_LO(v5) + BF_LO(v6) + BF_LO(v7);
        b1 += BF_HI(v4) + BF_HI(v5) + BF_HI(v6) + BF_HI(v7);
    }
    float2 pr;
    pr.x = a0 + b0;
    pr.y = a1 + b1;
    *(float2*)&red[wv][lane * 2] = pr;
    __syncthreads();

    if (tid < 128) {
        float s = ((red[0][tid] + red[1][tid]) + (red[2][tid] + red[3][tid]))
                + ((red[4][tid] + red[5][tid]) + (red[6][tid] + red[7][tid]));
        float v = state[(size_t)j * 256 + tid] + s;
        state[(size_t)j * 256 + tid] = v;
        __hip_bfloat16 h = __float2bfloat16(v);
        mirror[(size_t)j * 128 + tid] = *(uint16_t*)&h;
    }
}

extern "C" void kernel_launch(void* const* d_in, const int* in_sizes, int n_in,
                              void* d_out, int out_size, void* d_ws, size_t ws_size,
                              hipStream_t stream) {
    const int*   inputs  = (const int*)d_in[0];
    const float* first_a = (const float*)d_in[1];
    const float* first_t = (const float*)d_in[2];
    const float* Awij    = (const float*)d_in[3];
    const float* Awij2   = (const float*)d_in[4];
    float* out = (float*)d_out;

    // workspace layout (48 MiB total)
    char* w = (char*)d_ws;
    int*      inputsT = (int*)(w);                      // 4 MiB
    uint16_t* W2T     = (uint16_t*)(w + (4u << 20));    // 4 MiB  [(l,a)][e]
    uint16_t* W1T     = (uint16_t*)(w + (8u << 20));    // 4 MiB  [(l,e)][a]
    uint16_t* srcAb   = (uint16_t*)(w + (12u << 20));   // 256 KiB bf16 mirror of stateA
    uint16_t* srcTb   = (uint16_t*)(w + (12u << 20) + (1u << 18)); // 256 KiB mirror of stateT
    uint16_t* proj16  = (uint16_t*)(w + (16u << 20));   // 32 MiB  [1024][16384] bf16
    if (ws_size < (48u << 20)) return;

    float* stateA = out;                 // [1024][256], cols 0..127 live
    float* stateT = out + 1024 * 256;    // [1024][256], cols 0..127 live

    transpose_int_kernel<<<1024, 256, 0, stream>>>(inputs, inputsT);
    transpose_w_kernel<<<4096, 256, 0, stream>>>(Awij2, Awij, W2T, W1T);
    init_out_kernel<<<2048, 256, 0, stream>>>(first_a, first_t, out, srcAb, srcTb);

    for (int s = 0; s < 2; ++s) {
        // Phase A: t_proj = t_mirror x W2T^T; a[j] += sum_t t_proj[t, inputs[j,t], :]
        proj_kernel<<<1024, 512, 0, stream>>>(srcTb, W2T, proj16);
        gather_kernel<<<1024, 512, 0, stream>>>(inputs, (const uint32_t*)proj16, stateA, srcAb);
        // Phase T: a_proj = a_mirror x W1T^T; t[k] += sum_j a_proj[j, inputs[j,k], :]
        proj_kernel<<<1024, 512, 0, stream>>>(srcAb, W1T, proj16);
        gather_kernel<<<1024, 512, 0, stream>>>(inputsT, (const uint32_t*)proj16, stateT, srcTb);
    }
}

// Round 11
// 170.127 us; speedup vs baseline: 1.3903x; 1.1588x over previous
//
#include <hip/hip_runtime.h>
#include <hip/hip_bf16.h>
#include <stdint.h>

// Problem constants: NA=NT=1024, A_DIM=E_DIM=128, L=128

typedef short bf16x8 __attribute__((ext_vector_type(8)));
typedef float f32x4  __attribute__((ext_vector_type(4)));

#define GLD16(g, l) __builtin_amdgcn_global_load_lds( \
    (const __attribute__((address_space(1))) void*)(uintptr_t)(g), \
    (__attribute__((address_space(3))) void*)(uintptr_t)(l), 16, 0, 0)

#define BF_LO(v) __uint_as_float((v) << 16)
#define BF_HI(v) __uint_as_float((v) & 0xffff0000u)

static __device__ __forceinline__ uint32_t pk2(float lo, float hi) {
    __hip_bfloat16 h0 = __float2bfloat16(lo), h1 = __float2bfloat16(hi);
    return ((uint32_t)(*(uint16_t*)&h1) << 16) | (uint32_t)(*(uint16_t*)&h0);
}

// ---------------- prep: transpose inputs [1024][1024] -> inputsT ----------------
__global__ __launch_bounds__(256) void transpose_int_kernel(const int* __restrict__ in,
                                                            int* __restrict__ out) {
    __shared__ int tile[32][33];
    int b = blockIdx.x;              // 1024 tiles
    int tr = b >> 5, tc = b & 31;
    int r0 = tr * 32, c0 = tc * 32;
    int tx = threadIdx.x & 31, ty = threadIdx.x >> 5;
#pragma unroll
    for (int p = 0; p < 4; ++p)
        tile[ty + p * 8][tx] = in[(size_t)(r0 + ty + p * 8) * 1024 + c0 + tx];
    __syncthreads();
#pragma unroll
    for (int p = 0; p < 4; ++p) {
        int cc = ty + p * 8;
        out[(size_t)(c0 + cc) * 1024 + r0 + tx] = tile[tx][cc];
    }
}

// ------- prep: per-label 128x128 transpose + bf16 cast -------
// W2T[(l*128+a)][e] = Awij2[l][e][a]   (phase A: t_proj[t,(l,a)] = sum_e t[t,e]*Awij2[l,e,a])
// W1T[(l*128+e)][a] = Awij [l][a][e]   (phase T)
__global__ __launch_bounds__(256) void transpose_w_kernel(const float* __restrict__ W2,
                                                          const float* __restrict__ W1,
                                                          uint16_t* __restrict__ O2T,
                                                          uint16_t* __restrict__ O1T) {
    __shared__ float tile[32][33];
    int b = blockIdx.x;              // 4096 = 2 weights x 128 l x 16 subtiles
    const float* W = W2;
    uint16_t* O = O2T;
    if (b >= 2048) { b -= 2048; W = W1; O = O1T; }
    int l = b >> 4, sub = b & 15;
    int x0 = (sub >> 2) * 32, y0 = (sub & 3) * 32;   // src[l][x][y], 128x128
    int tx = threadIdx.x & 31, ty = threadIdx.x >> 5;
#pragma unroll
    for (int p = 0; p < 4; ++p)
        tile[ty + p * 8][tx] = W[(size_t)l * 16384 + (size_t)(x0 + ty + p * 8) * 128 + y0 + tx];
    __syncthreads();
#pragma unroll
    for (int p = 0; p < 4; ++p) {
        int yy = ty + p * 8;
        __hip_bfloat16 h = __float2bfloat16(tile[tx][yy]);   // dst[y][x] = src[x][y]
        O[(size_t)(l * 128 + y0 + yy) * 128 + x0 + tx] = *(uint16_t*)&h;
    }
}

// ---------------- prep: init output + bf16 mirrors ----------------
__global__ __launch_bounds__(256) void init_out_kernel(const float* __restrict__ fa,
                                                       const float* __restrict__ ft,
                                                       float* __restrict__ out,
                                                       uint16_t* __restrict__ srcAb,
                                                       uint16_t* __restrict__ srcTb) {
    int i = blockIdx.x * 256 + threadIdx.x;   // grid 2048 -> 524288
    int r = i >> 8, c = i & 255;
    float v = 0.f;
    if (c < 128) {
        v = (r < 1024) ? fa[(size_t)r * 128 + c] : ft[(size_t)(r - 1024) * 128 + c];
        __hip_bfloat16 h = __float2bfloat16(v);
        if (r < 1024) srcAb[(size_t)r * 128 + c] = *(uint16_t*)&h;
        else          srcTb[(size_t)(r - 1024) * 128 + c] = *(uint16_t*)&h;
    }
    out[i] = v;
}

// ---------------- proj: P[1024][16384] = src[1024][128] x WT[16384][128]^T (bf16, K=128) ----------------
// grid 1024 linear, XCD-chunked. 8 waves (2x4), wave tile 64x32, swapped-operand MFMA.
__global__ __launch_bounds__(512, 2) void proj_kernel(const uint16_t* __restrict__ src,  // [1024][128]
                                                      const uint16_t* __restrict__ WT,   // [16384][128]
                                                      uint16_t* __restrict__ proj) {     // [1024][16384]
    __shared__ uint16_t At[128 * 128];   // 32 KiB, 16B-slot XOR-swizzled by row&15
    __shared__ uint16_t Bt[128 * 128];

    const int tid = threadIdx.x;
    const int lane = tid & 63, wv = tid >> 6;
    const int bid = blockIdx.x;
    const int virt = (bid & 7) * 128 + (bid >> 3);   // bijective, 8 XCD chunks
    const int mt = virt & 7;            // 0..7
    const int nt = virt >> 3;           // 0..127
    const int wr = wv >> 2, wc = wv & 3;

    const int rr = lane >> 4;           // 0..3
    const int sx16 = lane & 15;
#pragma unroll
    for (int g = 0; g < 4; ++g) {
        int row = wv * 16 + g * 4 + rr;
        int sx = sx16 ^ (row & 15);     // pre-swizzled source (involution)
        GLD16((const char*)src + ((size_t)(mt * 128 + row) * 128 + sx * 8) * 2,
              (char*)At + (wv * 16 + g * 4) * 256);
        GLD16((const char*)WT + ((size_t)(nt * 128 + row) * 128 + sx * 8) * 2,
              (char*)Bt + (wv * 16 + g * 4) * 256);
    }
    __syncthreads();   // drains GLD16 vmcnt

    f32x4 acc[4][2] = {};
    const int q = lane >> 4, rl = lane & 15;
#pragma unroll
    for (int kk = 0; kk < 4; ++kk) {
        bf16x8 af[4], bfr[2];
#pragma unroll
        for (int m = 0; m < 4; ++m) {
            int row = wr * 64 + m * 16 + rl;
            int sw = (kk * 4 + q) ^ (row & 15);
            af[m] = *(const bf16x8*)((const char*)At + row * 256 + sw * 16);
        }
#pragma unroll
        for (int n = 0; n < 2; ++n) {
            int row = wc * 32 + n * 16 + rl;
            int sw = (kk * 4 + q) ^ (row & 15);
            bfr[n] = *(const bf16x8*)((const char*)Bt + row * 256 + sw * 16);
        }
#pragma unroll
        for (int m = 0; m < 4; ++m)
#pragma unroll
            for (int n = 0; n < 2; ++n)   // swapped operands -> D = C^T fragment
                acc[m][n] = __builtin_amdgcn_mfma_f32_16x16x32_bf16(bfr[n], af[m], acc[m][n], 0, 0, 0);
    }

    // C^T frag: col(lane&15) = m-space, row(q*4+reg) = n-space -> regs are 4 consecutive n.
#pragma unroll
    for (int m = 0; m < 4; ++m)
#pragma unroll
        for (int n = 0; n < 2; ++n) {
            int mrow = mt * 128 + wr * 64 + m * 16 + rl;
            int ncol = nt * 128 + wc * 32 + n * 16 + q * 4;
            uint2 pk;
            pk.x = pk2(acc[m][n][0], acc[m][n][1]);
            pk.y = pk2(acc[m][n][2], acc[m][n][3]);
            *(uint2*)(proj + (size_t)mrow * 16384 + ncol) = pk;
        }
}

// ---------------- gather partial: partial[j][ts] = sum_{t in slice ts} proj[t, lab[j][t], :] ----------------
// Block (j, ts) with bid = j*8+ts -> XCD ts owns slice proj[ts*128..+128] (4 MiB, L2-resident).
// 4 waves x 32 edges; lane covers channels (2lane, 2lane+1); 8 loads in flight.
__global__ __launch_bounds__(256, 8) void gather_partial_kernel(
    const int* __restrict__ labels,     // [1024][1024]
    const uint32_t* __restrict__ proj,  // [1024][8192] u32 view
    float* __restrict__ partial)        // [1024][8][128]
{
    __shared__ uint16_t lab16[128];
    __shared__ float red[4][128];
    const int bid = blockIdx.x;
    const int j = bid >> 3, ts = bid & 7;
    const int tid = threadIdx.x;
    const int lane = tid & 63, wv = tid >> 6;

    if (tid < 128) lab16[tid] = (uint16_t)labels[(size_t)j * 1024 + ts * 128 + tid];
    __syncthreads();

    float a0 = 0.f, a1 = 0.f, b0 = 0.f, b1 = 0.f;
    const uint32_t lane_u = (uint32_t)lane;
    const int t0 = ts * 128 + wv * 32;
#pragma unroll 1
    for (int i = 0; i < 32; i += 8) {
        ushort4 L0 = *(const ushort4*)&lab16[wv * 32 + i];       // ds_read_b64
        ushort4 L1 = *(const ushort4*)&lab16[wv * 32 + i + 4];
        const uint32_t* base = proj + (size_t)(t0 + i) * 8192 + lane_u;
        uint32_t v0 = base[(uint32_t)L0.x * 64];
        uint32_t v1 = base[8192u + (uint32_t)L0.y * 64];
        uint32_t v2 = base[16384u + (uint32_t)L0.z * 64];
        uint32_t v3 = base[24576u + (uint32_t)L0.w * 64];
        uint32_t v4 = base[32768u + (uint32_t)L1.x * 64];
        uint32_t v5 = base[40960u + (uint32_t)L1.y * 64];
        uint32_t v6 = base[49152u + (uint32_t)L1.z * 64];
        uint32_t v7 = base[57344u + (uint32_t)L1.w * 64];
        a0 += BF_LO(v0) + BF_LO(v1) + BF_LO(v2) + BF_LO(v3);
        a1 += BF_HI(v0) + BF_HI(v1) + BF_HI(v2) + BF_HI(v3);
        b0 += BF_LO(v4) + BF_LO(v5) + BF_LO(v6) + BF_LO(v7);
        b1 += BF_HI(v4) + BF_HI(v5) + BF_HI(v6) + BF_HI(v7);
    }
    float2 pr;
    pr.x = a0 + b0;
    pr.y = a1 + b1;
    *(float2*)&red[wv][lane * 2] = pr;
    __syncthreads();

    if (tid < 128) {
        float s = (red[0][tid] + red[1][tid]) + (red[2][tid] + red[3][tid]);
        partial[((size_t)j * 8 + ts) * 128 + tid] = s;
    }
}

// ---------------- reduce 8 slice-partials + update state + emit bf16 mirror ----------------
__global__ __launch_bounds__(256) void reduce_state_kernel(const float* __restrict__ partial,
                                                           float* __restrict__ state,
                                                           uint16_t* __restrict__ mirror) {
    int i = blockIdx.x * 256 + threadIdx.x;   // grid 512 -> 131072
    int j = i >> 7, c = i & 127;
    const float* p = partial + (size_t)j * 1024 + c;
    float s = ((p[0] + p[128]) + (p[256] + p[384])) + ((p[512] + p[640]) + (p[768] + p[896]));
    float v = state[(size_t)j * 256 + c] + s;
    state[(size_t)j * 256 + c] = v;
    __hip_bfloat16 h = __float2bfloat16(v);
    mirror[(size_t)j * 128 + c] = *(uint16_t*)&h;
}

extern "C" void kernel_launch(void* const* d_in, const int* in_sizes, int n_in,
                              void* d_out, int out_size, void* d_ws, size_t ws_size,
                              hipStream_t stream) {
    const int*   inputs  = (const int*)d_in[0];
    const float* first_a = (const float*)d_in[1];
    const float* first_t = (const float*)d_in[2];
    const float* Awij    = (const float*)d_in[3];
    const float* Awij2   = (const float*)d_in[4];
    float* out = (float*)d_out;

    // workspace layout (52 MiB total)
    char* w = (char*)d_ws;
    int*      inputsT = (int*)(w);                      // 4 MiB
    uint16_t* W2T     = (uint16_t*)(w + (4u << 20));    // 4 MiB  [(l,a)][e]
    uint16_t* W1T     = (uint16_t*)(w + (8u << 20));    // 4 MiB  [(l,e)][a]
    uint16_t* srcAb   = (uint16_t*)(w + (12u << 20));   // 256 KiB bf16 mirror of stateA
    uint16_t* srcTb   = (uint16_t*)(w + (12u << 20) + (1u << 19)); // 256 KiB mirror of stateT
    float*    partial = (float*)(w + (13u << 20));      // 4 MiB  [1024][8][128]
    uint16_t* proj16  = (uint16_t*)(w + (20u << 20));   // 32 MiB [1024][16384] bf16
    if (ws_size < (52u << 20)) return;

    float* stateA = out;                 // [1024][256], cols 0..127 live
    float* stateT = out + 1024 * 256;    // [1024][256], cols 0..127 live

    transpose_int_kernel<<<1024, 256, 0, stream>>>(inputs, inputsT);
    transpose_w_kernel<<<4096, 256, 0, stream>>>(Awij2, Awij, W2T, W1T);
    init_out_kernel<<<2048, 256, 0, stream>>>(first_a, first_t, out, srcAb, srcTb);

    for (int s = 0; s < 2; ++s) {
        // Phase A: t_proj = t_mirror x W2T^T; a[j] += sum_t t_proj[t, inputs[j,t], :]
        proj_kernel<<<1024, 512, 0, stream>>>(srcTb, W2T, proj16);
        gather_partial_kernel<<<8192, 256, 0, stream>>>(inputs, (const uint32_t*)proj16, partial);
        reduce_state_kernel<<<512, 256, 0, stream>>>(partial, stateA, srcAb);
        // Phase T: a_proj = a_mirror x W1T^T; t[k] += sum_j a_proj[j, inputs[j,k], :]
        proj_kernel<<<1024, 512, 0, stream>>>(srcAb, W1T, proj16);
        gather_partial_kernel<<<8192, 256, 0, stream>>>(inputsT, (const uint32_t*)proj16, partial);
        reduce_state_kernel<<<512, 256, 0, stream>>>(partial, stateT, srcTb);
    }
}

// Round 12
// 168.486 us; speedup vs baseline: 1.4038x; 1.0097x over previous
//
#include <hip/hip_runtime.h>
#include <hip/hip_bf16.h>
#include <stdint.h>

// Problem constants: NA=NT=1024, A_DIM=E_DIM=128, L=128

typedef short bf16x8 __attribute__((ext_vector_type(8)));
typedef float f32x4  __attribute__((ext_vector_type(4)));

#define GLD16(g, l) __builtin_amdgcn_global_load_lds( \
    (const __attribute__((address_space(1))) void*)(uintptr_t)(g), \
    (__attribute__((address_space(3))) void*)(uintptr_t)(l), 16, 0, 0)

#define BF_LO(v) __uint_as_float((v) << 16)
#define BF_HI(v) __uint_as_float((v) & 0xffff0000u)

static __device__ __forceinline__ uint32_t pk2(float lo, float hi) {
    __hip_bfloat16 h0 = __float2bfloat16(lo), h1 = __float2bfloat16(hi);
    return ((uint32_t)(*(uint16_t*)&h1) << 16) | (uint32_t)(*(uint16_t*)&h0);
}

// ---------------- fused prep: inputs transpose + weight transposes + init ----------------
// b < 1024         : transpose inputs tile
// 1024 <= b < 5120 : per-label 128x128 weight transpose + bf16 cast
//                    W2T[(l*128+a)][e] = Awij2[l][e][a], W1T[(l*128+e)][a] = Awij[l][a][e]
// 5120 <= b < 7168 : init output + bf16 mirrors
__global__ __launch_bounds__(256) void prep_kernel(const int* __restrict__ in,
                                                   int* __restrict__ inT,
                                                   const float* __restrict__ W2,
                                                   const float* __restrict__ W1,
                                                   uint16_t* __restrict__ O2T,
                                                   uint16_t* __restrict__ O1T,
                                                   const float* __restrict__ fa,
                                                   const float* __restrict__ ft,
                                                   float* __restrict__ out,
                                                   uint16_t* __restrict__ srcAb,
                                                   uint16_t* __restrict__ srcTb) {
    __shared__ float tile[32][33];
    int b = blockIdx.x;
    int tx = threadIdx.x & 31, ty = threadIdx.x >> 5;

    if (b < 1024) {                       // ---- transpose inputs ----
        int tr = b >> 5, tc = b & 31;
        int r0 = tr * 32, c0 = tc * 32;
#pragma unroll
        for (int p = 0; p < 4; ++p)
            tile[ty + p * 8][tx] = __int_as_float(in[(size_t)(r0 + ty + p * 8) * 1024 + c0 + tx]);
        __syncthreads();
#pragma unroll
        for (int p = 0; p < 4; ++p) {
            int cc = ty + p * 8;
            inT[(size_t)(c0 + cc) * 1024 + r0 + tx] = __float_as_int(tile[tx][cc]);
        }
    } else if (b < 5120) {                // ---- weight transpose + cast ----
        int bb = b - 1024;
        const float* W = W2;
        uint16_t* O = O2T;
        if (bb >= 2048) { bb -= 2048; W = W1; O = O1T; }
        int l = bb >> 4, sub = bb & 15;
        int x0 = (sub >> 2) * 32, y0 = (sub & 3) * 32;
#pragma unroll
        for (int p = 0; p < 4; ++p)
            tile[ty + p * 8][tx] = W[(size_t)l * 16384 + (size_t)(x0 + ty + p * 8) * 128 + y0 + tx];
        __syncthreads();
#pragma unroll
        for (int p = 0; p < 4; ++p) {
            int yy = ty + p * 8;
            __hip_bfloat16 h = __float2bfloat16(tile[tx][yy]);
            O[(size_t)(l * 128 + y0 + yy) * 128 + x0 + tx] = *(uint16_t*)&h;
        }
    } else {                              // ---- init output + mirrors ----
        int i = (b - 5120) * 256 + threadIdx.x;
        int r = i >> 8, c = i & 255;
        float v = 0.f;
        if (c < 128) {
            v = (r < 1024) ? fa[(size_t)r * 128 + c] : ft[(size_t)(r - 1024) * 128 + c];
            __hip_bfloat16 h = __float2bfloat16(v);
            if (r < 1024) srcAb[(size_t)r * 128 + c] = *(uint16_t*)&h;
            else          srcTb[(size_t)(r - 1024) * 128 + c] = *(uint16_t*)&h;
        }
        out[i] = v;
    }
}

// ---------------- proj: P[1024][16384] = src[1024][128] x WT[16384][128]^T (bf16, K=128) ----------------
// mt = bid&7: XCD x computes/writes the ROW-slab t in [x*128,+128) that gather on XCD x reads
// (proj output stays dirty-resident in that XCD's L2). 8 waves (2x4), swapped-operand MFMA.
__global__ __launch_bounds__(512, 2) void proj_kernel(const uint16_t* __restrict__ src,  // [1024][128]
                                                      const uint16_t* __restrict__ WT,   // [16384][128]
                                                      uint16_t* __restrict__ proj) {     // [1024][16384]
    __shared__ uint16_t At[128 * 128];   // 32 KiB, 16B-slot XOR-swizzled by row&15
    __shared__ uint16_t Bt[128 * 128];

    const int tid = threadIdx.x;
    const int lane = tid & 63, wv = tid >> 6;
    const int bid = blockIdx.x;
    const int mt = bid & 7;             // row-slab == XCD (round-robin dispatch)
    const int nt = bid >> 3;            // 0..127
    const int wr = wv >> 2, wc = wv & 3;

    const int rr = lane >> 4;           // 0..3
    const int sx16 = lane & 15;
#pragma unroll
    for (int g = 0; g < 4; ++g) {
        int row = wv * 16 + g * 4 + rr;
        int sx = sx16 ^ (row & 15);     // pre-swizzled source (involution)
        GLD16((const char*)src + ((size_t)(mt * 128 + row) * 128 + sx * 8) * 2,
              (char*)At + (wv * 16 + g * 4) * 256);
        GLD16((const char*)WT + ((size_t)(nt * 128 + row) * 128 + sx * 8) * 2,
              (char*)Bt + (wv * 16 + g * 4) * 256);
    }
    __syncthreads();   // drains GLD16 vmcnt

    f32x4 acc[4][2] = {};
    const int q = lane >> 4, rl = lane & 15;
#pragma unroll
    for (int kk = 0; kk < 4; ++kk) {
        bf16x8 af[4], bfr[2];
#pragma unroll
        for (int m = 0; m < 4; ++m) {
            int row = wr * 64 + m * 16 + rl;
            int sw = (kk * 4 + q) ^ (row & 15);
            af[m] = *(const bf16x8*)((const char*)At + row * 256 + sw * 16);
        }
#pragma unroll
        for (int n = 0; n < 2; ++n) {
            int row = wc * 32 + n * 16 + rl;
            int sw = (kk * 4 + q) ^ (row & 15);
            bfr[n] = *(const bf16x8*)((const char*)Bt + row * 256 + sw * 16);
        }
#pragma unroll
        for (int m = 0; m < 4; ++m)
#pragma unroll
            for (int n = 0; n < 2; ++n)   // swapped operands -> D = C^T fragment
                acc[m][n] = __builtin_amdgcn_mfma_f32_16x16x32_bf16(bfr[n], af[m], acc[m][n], 0, 0, 0);
    }

    // C^T frag: col(lane&15) = m-space, row(q*4+reg) = n-space -> regs are 4 consecutive n.
#pragma unroll
    for (int m = 0; m < 4; ++m)
#pragma unroll
        for (int n = 0; n < 2; ++n) {
            int mrow = mt * 128 + wr * 64 + m * 16 + rl;
            int ncol = nt * 128 + wc * 32 + n * 16 + q * 4;
            uint2 pk;
            pk.x = pk2(acc[m][n][0], acc[m][n][1]);
            pk.y = pk2(acc[m][n][2], acc[m][n][3]);
            *(uint2*)(proj + (size_t)mrow * 16384 + ncol) = pk;
        }
}

// ---------------- gather partial: partial[j][ts] = sum_{t in slice ts} proj[t, lab[j][t], :] ----------------
// Block (j, ts), bid = j*8+ts -> XCD ts reads its own L2-resident 4 MiB slice.
// Labels are wave-uniform: readfirstlane -> SGPR addressing (SALU, not VALU).
// 16 loads in flight per wave, 8 accumulator trees.
__global__ __launch_bounds__(256, 8) void gather_partial_kernel(
    const int* __restrict__ labels,     // [1024][1024]
    const uint32_t* __restrict__ proj,  // [1024][8192] u32 view
    float* __restrict__ partial)        // [1024][8][128]
{
    __shared__ uint16_t lab16[128];
    __shared__ float red[4][128];
    const int bid = blockIdx.x;
    const int j = bid >> 3, ts = bid & 7;
    const int tid = threadIdx.x;
    const int lane = tid & 63, wv = tid >> 6;

    if (tid < 128) lab16[tid] = (uint16_t)labels[(size_t)j * 1024 + ts * 128 + tid];
    __syncthreads();

    const uint32_t lane_u = (uint32_t)lane;
    const uint32_t* tb = proj + (size_t)(ts * 128 + wv * 32) * 8192 + lane_u;
    float a0 = 0.f, a1 = 0.f, b0 = 0.f, b1 = 0.f;
    float c0 = 0.f, c1 = 0.f, d0 = 0.f, d1 = 0.f;

#pragma unroll 1
    for (int i = 0; i < 32; i += 16) {
        int L[16];
#pragma unroll
        for (int g = 0; g < 4; ++g) {
            ushort4 q = *(const ushort4*)&lab16[wv * 32 + i + g * 4];   // wave-uniform ds_read_b64
            L[g * 4 + 0] = __builtin_amdgcn_readfirstlane((int)q.x);
            L[g * 4 + 1] = __builtin_amdgcn_readfirstlane((int)q.y);
            L[g * 4 + 2] = __builtin_amdgcn_readfirstlane((int)q.z);
            L[g * 4 + 3] = __builtin_amdgcn_readfirstlane((int)q.w);
        }
        uint32_t v[16];
#pragma unroll
        for (int e = 0; e < 16; ++e)     // scalar offset -> saddr-form loads, 16 in flight
            v[e] = tb[(uint32_t)(i + e) * 8192u + (uint32_t)L[e] * 64u];

        a0 += BF_LO(v[0]) + BF_LO(v[1]) + BF_LO(v[2]) + BF_LO(v[3]);
        a1 += BF_HI(v[0]) + BF_HI(v[1]) + BF_HI(v[2]) + BF_HI(v[3]);
        b0 += BF_LO(v[4]) + BF_LO(v[5]) + BF_LO(v[6]) + BF_LO(v[7]);
        b1 += BF_HI(v[4]) + BF_HI(v[5]) + BF_HI(v[6]) + BF_HI(v[7]);
        c0 += BF_LO(v[8]) + BF_LO(v[9]) + BF_LO(v[10]) + BF_LO(v[11]);
        c1 += BF_HI(v[8]) + BF_HI(v[9]) + BF_HI(v[10]) + BF_HI(v[11]);
        d0 += BF_LO(v[12]) + BF_LO(v[13]) + BF_LO(v[14]) + BF_LO(v[15]);
        d1 += BF_HI(v[12]) + BF_HI(v[13]) + BF_HI(v[14]) + BF_HI(v[15]);
    }
    float2 pr;
    pr.x = (a0 + b0) + (c0 + d0);
    pr.y = (a1 + b1) + (c1 + d1);
    *(float2*)&red[wv][lane * 2] = pr;
    __syncthreads();

    if (tid < 128) {
        float s = (red[0][tid] + red[1][tid]) + (red[2][tid] + red[3][tid]);
        partial[((size_t)j * 8 + ts) * 128 + tid] = s;
    }
}

// ---------------- reduce 8 slice-partials + update state + emit bf16 mirror ----------------
__global__ __launch_bounds__(256) void reduce_state_kernel(const float* __restrict__ partial,
                                                           float* __restrict__ state,
                                                           uint16_t* __restrict__ mirror) {
    int i = blockIdx.x * 256 + threadIdx.x;   // grid 512 -> 131072
    int j = i >> 7, c = i & 127;
    const float* p = partial + (size_t)j * 1024 + c;
    float s = ((p[0] + p[128]) + (p[256] + p[384])) + ((p[512] + p[640]) + (p[768] + p[896]));
    float v = state[(size_t)j * 256 + c] + s;
    state[(size_t)j * 256 + c] = v;
    __hip_bfloat16 h = __float2bfloat16(v);
    mirror[(size_t)j * 128 + c] = *(uint16_t*)&h;
}

extern "C" void kernel_launch(void* const* d_in, const int* in_sizes, int n_in,
                              void* d_out, int out_size, void* d_ws, size_t ws_size,
                              hipStream_t stream) {
    const int*   inputs  = (const int*)d_in[0];
    const float* first_a = (const float*)d_in[1];
    const float* first_t = (const float*)d_in[2];
    const float* Awij    = (const float*)d_in[3];
    const float* Awij2   = (const float*)d_in[4];
    float* out = (float*)d_out;

    // workspace layout (52 MiB total)
    char* w = (char*)d_ws;
    int*      inputsT = (int*)(w);                      // 4 MiB
    uint16_t* W2T     = (uint16_t*)(w + (4u << 20));    // 4 MiB  [(l,a)][e]
    uint16_t* W1T     = (uint16_t*)(w + (8u << 20));    // 4 MiB  [(l,e)][a]
    uint16_t* srcAb   = (uint16_t*)(w + (12u << 20));   // 256 KiB bf16 mirror of stateA
    uint16_t* srcTb   = (uint16_t*)(w + (12u << 20) + (1u << 19)); // 256 KiB mirror of stateT
    float*    partial = (float*)(w + (13u << 20));      // 4 MiB  [1024][8][128]
    uint16_t* proj16  = (uint16_t*)(w + (20u << 20));   // 32 MiB [1024][16384] bf16
    if (ws_size < (52u << 20)) return;

    float* stateA = out;                 // [1024][256], cols 0..127 live
    float* stateT = out + 1024 * 256;    // [1024][256], cols 0..127 live

    prep_kernel<<<7168, 256, 0, stream>>>(inputs, inputsT, Awij2, Awij, W2T, W1T,
                                          first_a, first_t, out, srcAb, srcTb);

    for (int s = 0; s < 2; ++s) {
        // Phase A: t_proj = t_mirror x W2T^T; a[j] += sum_t t_proj[t, inputs[j,t], :]
        proj_kernel<<<1024, 512, 0, stream>>>(srcTb, W2T, proj16);
        gather_partial_kernel<<<8192, 256, 0, stream>>>(inputs, (const uint32_t*)proj16, partial);
        reduce_state_kernel<<<512, 256, 0, stream>>>(partial, stateA, srcAb);
        // Phase T: a_proj = a_mirror x W1T^T; t[k] += sum_j a_proj[j, inputs[j,k], :]
        proj_kernel<<<1024, 512, 0, stream>>>(srcAb, W1T, proj16);
        gather_partial_kernel<<<8192, 256, 0, stream>>>(inputsT, (const uint32_t*)proj16, partial);
        reduce_state_kernel<<<512, 256, 0, stream>>>(partial, stateT, srcTb);
    }
}